// Round 6
// baseline (1767.519 us; speedup 1.0000x reference)
//
#include <hip/hip_runtime.h>

#define NN 50000
#define EE 800000
#define GG 64
#define FF 128
#define NBES 8
#define RMAXF 5.0f
#define PI_F 3.14159265358979323846f

// spherical harmonic constants
#define S3  1.7320508075688772f
#define S5  2.23606797749979f
#define S15 3.872983346207417f
#define C1c 2.091650066335189f   // sqrt(35/8)
#define C2c 10.246950765959598f  // sqrt(105)
#define C3c 1.62018517460196f    // sqrt(21/8)
#define C4c 1.3228756555322954f  // sqrt(7)/2
#define C5c 5.123475382979799f   // sqrt(105)/2
#define CCB 0.6324555320336759f  // sqrt(2/5)

__device__ __forceinline__ float shc_s(float x, float y, float z, const float* __restrict__ w) {
    float x2 = x * x, y2 = y * y, z2 = z * z;
    return w[0]
        + w[1] * (S3 * x) + w[2] * (S3 * y) + w[3] * (S3 * z)
        + w[4] * (S15 * x * y) + w[5] * (S15 * y * z) + w[6] * (0.5f * S5 * (3.f * z2 - 1.f))
        + w[7] * (S15 * x * z) + w[8] * (0.5f * S15 * (x2 - y2))
        + w[9] * (C1c * y * (3.f * x2 - y2)) + w[10] * (C2c * x * y * z)
        + w[11] * (C3c * y * (5.f * z2 - 1.f)) + w[12] * (C4c * z * (5.f * z2 - 3.f))
        + w[13] * (C3c * x * (5.f * z2 - 1.f)) + w[14] * (C5c * z * (x2 - y2))
        + w[15] * (C1c * x * (x2 - 3.f * y2));
}

__device__ __forceinline__ void shc_grad(float x, float y, float z, const float* __restrict__ w,
                                         float& gx, float& gy, float& gz) {
    float x2 = x * x, y2 = y * y, z2 = z * z;
    gx = w[1] * S3 + w[4] * (S15 * y) + w[7] * (S15 * z) + w[8] * (S15 * x)
       + w[9] * (6.f * C1c * x * y) + w[10] * (C2c * y * z) + w[13] * (C3c * (5.f * z2 - 1.f))
       + w[14] * (2.f * C5c * x * z) + w[15] * (3.f * C1c * (x2 - y2));
    gy = w[2] * S3 + w[4] * (S15 * x) + w[5] * (S15 * z) - w[8] * (S15 * y)
       + w[9] * (3.f * C1c * (x2 - y2)) + w[10] * (C2c * x * z) + w[11] * (C3c * (5.f * z2 - 1.f))
       - w[14] * (2.f * C5c * y * z) - w[15] * (6.f * C1c * x * y);
    gz = w[3] * S3 + w[5] * (S15 * y) + w[6] * (3.f * S5 * z) + w[7] * (S15 * x)
       + w[10] * (C2c * x * y) + w[11] * (10.f * C3c * y * z) + w[12] * (C4c * (15.f * z2 - 3.f))
       + w[13] * (10.f * C3c * x * z) + w[14] * (C5c * (x2 - y2));
}

// geo SoA layout (arrays of EE floats)
#define G_EB(k)  ((size_t)(k) * EE)
#define G_S0     ((size_t)8 * EE)
#define G_S1     ((size_t)9 * EE)
#define G_DB(k)  ((size_t)(10 + (k)) * EE)
#define G_DSP0   ((size_t)18 * EE)
#define G_DRP0   ((size_t)19 * EE)
#define G_DSP1   ((size_t)20 * EE)
#define G_DRP1   ((size_t)21 * EE)

// -------------------- CSR build --------------------

__global__ __launch_bounds__(256) void count_kernel(const int* __restrict__ ei,
                                                    int* __restrict__ cnt) {
    int e = blockIdx.x * 256 + threadIdx.x;
    if (e >= EE) return;
    atomicAdd(&cnt[ei[EE + e]], 1);        // rcv counts
    atomicAdd(&cnt[NN + ei[e]], 1);        // snd counts
}

// one block per half (rcv / snd); 256 threads sequential chunked scan
__global__ __launch_bounds__(256) void scan_kernel(const int* __restrict__ cnt,
                                                   int* __restrict__ off) {
    const int* c = cnt + (size_t)blockIdx.x * NN;
    int* o = off + (size_t)blockIdx.x * (NN + 1);
    __shared__ int wsum[4];
    __shared__ int carry_s;
    if (threadIdx.x == 0) carry_s = 0;
    __syncthreads();
    int lane = threadIdx.x & 63;
    int wid = threadIdx.x >> 6;
    for (int base = 0; base < NN; base += 256) {
        int i = base + threadIdx.x;
        int v = (i < NN) ? c[i] : 0;
        int x = v;
#pragma unroll
        for (int d = 1; d < 64; d <<= 1) {
            int y = __shfl_up(x, d);
            if (lane >= d) x += y;
        }
        if (lane == 63) wsum[wid] = x;
        __syncthreads();
        int pre = 0;
#pragma unroll
        for (int w = 0; w < 4; w++) if (w < wid) pre += wsum[w];
        int total = wsum[0] + wsum[1] + wsum[2] + wsum[3];
        int carry = carry_s;
        if (i < NN) o[i] = carry + pre + x - v;
        __syncthreads();
        if (threadIdx.x == 0) carry_s = carry + total;
        __syncthreads();
    }
    if (threadIdx.x == 0) o[NN] = carry_s;
}

__global__ __launch_bounds__(256) void fill_kernel(const int* __restrict__ ei,
                                                   const int* __restrict__ off,
                                                   int* __restrict__ cur,
                                                   int* __restrict__ perm) {
    int e = blockIdx.x * 256 + threadIdx.x;
    if (e >= EE) return;
    int snd = ei[e], rcv = ei[EE + e];
    int p0 = off[rcv] + atomicAdd(&cur[rcv], 1);
    perm[p0] = e;
    int p1 = off[(NN + 1) + snd] + atomicAdd(&cur[NN + snd], 1);
    perm[EE + p1] = e;
}

// -------------------- geometry (thread-per-edge) --------------------

__global__ __launch_bounds__(256) void edge_geom(const float* __restrict__ pos,
                                                 const float* __restrict__ shifts,
                                                 const int* __restrict__ ei,
                                                 const float* __restrict__ wsh,
                                                 float* __restrict__ geo) {
    int e = blockIdx.x * 256 + threadIdx.x;
    if (e >= EE) return;
    int snd = ei[e];
    int rcv = ei[EE + e];
    float vx = pos[rcv * 3 + 0] - pos[snd * 3 + 0] + shifts[e * 3 + 0];
    float vy = pos[rcv * 3 + 1] - pos[snd * 3 + 1] + shifts[e * 3 + 1];
    float vz = pos[rcv * 3 + 2] - pos[snd * 3 + 2] + shifts[e * 3 + 2];
    float r2 = vx * vx + vy * vy + vz * vz + 1e-12f;
    float r = sqrtf(r2);
    float inv_r = 1.0f / r;
    float x = vx * inv_r, y = vy * inv_r, z = vz * inv_r;
    float valid = (r < RMAXF) ? 1.f : 0.f;

    geo[G_S0 + e] = shc_s(x, y, z, wsh);
    geo[G_S1 + e] = shc_s(x, y, z, wsh + 16);

    float u = r * (1.0f / RMAXF);
    float th = PI_F * u;
    float s1 = sinf(th), c1 = cosf(th);
    float u2 = u * u, u3 = u2 * u, u5 = u2 * u3, u6 = u3 * u3, u7 = u6 * u, u8 = u6 * u2;
    float env = (1.f - 28.f * u6 + 48.f * u7 - 21.f * u8) * valid;
    float denv = (-168.f * u5 + 336.f * u6 - 168.f * u7) * (1.0f / RMAXF) * valid;
    float sk = s1, skm = 0.f, ck = c1, ckm = 1.f;
    float tc = 2.f * c1;
#pragma unroll
    for (int k = 1; k <= NBES; k++) {
        float b = CCB * sk * inv_r;
        geo[G_EB(k - 1) + e] = b * env;
        geo[G_DB(k - 1) + e] = CCB * (((float)k * PI_F * (1.0f / RMAXF)) * ck * inv_r
                                      - sk * inv_r * inv_r) * env
                               + b * denv;
        float sn = tc * sk - skm; skm = sk; sk = sn;
        float cn = tc * ck - ckm; ckm = ck; ck = cn;
    }
}

// -------------------- node prep --------------------

__global__ __launch_bounds__(256) void h0_kernel(const float* __restrict__ attrs,
                                                 const float* __restrict__ W_emb,
                                                 float* __restrict__ h0) {
    int sub = threadIdx.x >> 7;
    int f = threadIdx.x & 127;
    int n = blockIdx.x * 2 + sub;
    float acc = 0.f;
#pragma unroll
    for (int a = 0; a < 10; a++) acc += attrs[n * 10 + a] * W_emb[a * FF + f];
    h0[n * FF + f] = acc;
}

// -------------------- CSR edge kernels (wave-per-node, grid-stride) --------------------

#define FEAT_BLOCKS 2048

// agg[n][f] = sum_{e: rcv=n} h_src[snd_e][f] * R_e[f] * s_e   (no atomics)
__global__ __launch_bounds__(256) void fwd_csr(const float* __restrict__ geo,
                                               const float* __restrict__ geo_s,
                                               const int* __restrict__ ei,
                                               const int* __restrict__ off_rcv,
                                               const int* __restrict__ perm_rcv,
                                               const float* __restrict__ h_src,
                                               const float* __restrict__ Wr,
                                               float* __restrict__ agg) {
    int wv = (blockIdx.x * 256 + threadIdx.x) >> 6;
    int lane = threadIdx.x & 63;
    int nwaves = FEAT_BLOCKS * 4;
    int f0 = lane, f1 = lane + 64;
    float wr0[NBES], wr1[NBES];
#pragma unroll
    for (int k = 0; k < NBES; k++) { wr0[k] = Wr[k * FF + f0]; wr1[k] = Wr[k * FF + f1]; }

    for (int n = wv; n < NN; n += nwaves) {
        int beg = off_rcv[n], end = off_rcv[n + 1];
        float acc0 = 0.f, acc1 = 0.f;
        for (int j = beg; j < end; j++) {
            int e = perm_rcv[j];
            int snd = ei[e];
            float s = geo_s[e];
            float R0 = 0.f, R1 = 0.f;
#pragma unroll
            for (int k = 0; k < NBES; k++) {
                float eb = geo[G_EB(k) + e];
                R0 += eb * wr0[k];
                R1 += eb * wr1[k];
            }
            acc0 += h_src[(size_t)snd * FF + f0] * R0 * s;
            acc1 += h_src[(size_t)snd * FF + f1] * R1 * s;
        }
        agg[(size_t)n * FF + f0] = acc0;
        agg[(size_t)n * FF + f1] = acc1;
    }
}

// layer-1 backward over snd-CSR: h1[n] and gh[n] in registers; no gather, no atomics.
__global__ __launch_bounds__(256) void bwd1_csr(const float* __restrict__ geo,
                                                const float* __restrict__ geo_s1,
                                                const int* __restrict__ off_snd,
                                                const int* __restrict__ perm_snd,
                                                const float* __restrict__ h1,
                                                const float* __restrict__ Wr1,
                                                const float* __restrict__ a1,
                                                const float* __restrict__ wread0,
                                                float* __restrict__ gh,
                                                float* __restrict__ dsp_out,
                                                float* __restrict__ drp_out) {
    int wv = (blockIdx.x * 256 + threadIdx.x) >> 6;
    int lane = threadIdx.x & 63;
    int nwaves = FEAT_BLOCKS * 4;
    int f0 = lane, f1 = lane + 64;
    float wr0[NBES], wr1[NBES];
#pragma unroll
    for (int k = 0; k < NBES; k++) { wr0[k] = Wr1[k * FF + f0]; wr1[k] = Wr1[k * FF + f1]; }
    float dm0 = a1[f0], dm1 = a1[f1];
    float w0 = wread0[f0], w1 = wread0[f1];

    for (int n = wv; n < NN; n += nwaves) {
        int beg = off_snd[n], end = off_snd[n + 1];
        float hh0 = h1[(size_t)n * FF + f0];
        float hh1 = h1[(size_t)n * FF + f1];
        float dh0 = dm0 * hh0, dh1 = dm1 * hh1;
        float g0 = 0.f, g1 = 0.f;
        for (int j = beg; j < end; j++) {
            int e = perm_snd[j];
            float R0 = 0.f, R1 = 0.f, Rd0 = 0.f, Rd1 = 0.f;
#pragma unroll
            for (int k = 0; k < NBES; k++) {
                float eb = geo[G_EB(k) + e];
                float db = geo[G_DB(k) + e];
                R0 += eb * wr0[k];
                R1 += eb * wr1[k];
                Rd0 += db * wr0[k];
                Rd1 += db * wr1[k];
            }
            float dsp = dh0 * R0 + dh1 * R1;
            float drp = dh0 * Rd0 + dh1 * Rd1;
#pragma unroll
            for (int o = 32; o > 0; o >>= 1) {
                dsp += __shfl_xor(dsp, o);
                drp += __shfl_xor(drp, o);
            }
            if (lane == 0) { dsp_out[e] = dsp; drp_out[e] = drp; }
            float s = geo_s1[e];
            g0 += dm0 * R0 * s;
            g1 += dm1 * R1 * s;
        }
        gh[(size_t)n * FF + f0] = w0 + g0;
        gh[(size_t)n * FF + f1] = w1 + g1;
    }
}

// layer-0 backward over rcv-CSR: b0[n] in registers; gather h0[snd].
__global__ __launch_bounds__(256) void bwd0_csr(const float* __restrict__ geo,
                                                const int* __restrict__ ei,
                                                const int* __restrict__ off_rcv,
                                                const int* __restrict__ perm_rcv,
                                                const float* __restrict__ h0,
                                                const float* __restrict__ Wr0,
                                                const float* __restrict__ b0,
                                                float* __restrict__ dsp_out,
                                                float* __restrict__ drp_out) {
    int wv = (blockIdx.x * 256 + threadIdx.x) >> 6;
    int lane = threadIdx.x & 63;
    int nwaves = FEAT_BLOCKS * 4;
    int f0 = lane, f1 = lane + 64;
    float wr0[NBES], wr1[NBES];
#pragma unroll
    for (int k = 0; k < NBES; k++) { wr0[k] = Wr0[k * FF + f0]; wr1[k] = Wr0[k * FF + f1]; }

    for (int n = wv; n < NN; n += nwaves) {
        int beg = off_rcv[n], end = off_rcv[n + 1];
        float dm0 = b0[(size_t)n * FF + f0];
        float dm1 = b0[(size_t)n * FF + f1];
        for (int j = beg; j < end; j++) {
            int e = perm_rcv[j];
            int snd = ei[e];
            float R0 = 0.f, R1 = 0.f, Rd0 = 0.f, Rd1 = 0.f;
#pragma unroll
            for (int k = 0; k < NBES; k++) {
                float eb = geo[G_EB(k) + e];
                float db = geo[G_DB(k) + e];
                R0 += eb * wr0[k];
                R1 += eb * wr1[k];
                Rd0 += db * wr0[k];
                Rd1 += db * wr1[k];
            }
            float dh0 = dm0 * h0[(size_t)snd * FF + f0];
            float dh1 = dm1 * h0[(size_t)snd * FF + f1];
            float dsp = dh0 * R0 + dh1 * R1;
            float drp = dh0 * Rd0 + dh1 * Rd1;
#pragma unroll
            for (int o = 32; o > 0; o >>= 1) {
                dsp += __shfl_xor(dsp, o);
                drp += __shfl_xor(drp, o);
            }
            if (lane == 0) { dsp_out[e] = dsp; drp_out[e] = drp; }
        }
    }
}

// -------------------- force finalize (thread-per-edge, both layers) --------------------

__global__ __launch_bounds__(256) void force_kernel(const float* __restrict__ pos,
                                                    const float* __restrict__ shifts,
                                                    const int* __restrict__ ei,
                                                    const float* __restrict__ wsh,
                                                    const float* __restrict__ geo,
                                                    float* __restrict__ forces) {
    int e = blockIdx.x * 256 + threadIdx.x;
    if (e >= EE) return;
    int snd = ei[e];
    int rcv = ei[EE + e];
    float vx = pos[rcv * 3 + 0] - pos[snd * 3 + 0] + shifts[e * 3 + 0];
    float vy = pos[rcv * 3 + 1] - pos[snd * 3 + 1] + shifts[e * 3 + 1];
    float vz = pos[rcv * 3 + 2] - pos[snd * 3 + 2] + shifts[e * 3 + 2];
    float r2 = vx * vx + vy * vy + vz * vz + 1e-12f;
    float r = sqrtf(r2);
    float inv_r = 1.0f / r;
    float x = vx * inv_r, y = vy * inv_r, z = vz * inv_r;

    float dsp0 = geo[G_DSP0 + e], drp0 = geo[G_DRP0 + e];
    float dsp1 = geo[G_DSP1 + e], drp1 = geo[G_DRP1 + e];
    float s0 = geo[G_S0 + e], s1v = geo[G_S1 + e];

    float g0x, g0y, g0z, g1x, g1y, g1z;
    shc_grad(x, y, z, wsh, g0x, g0y, g0z);
    shc_grad(x, y, z, wsh + 16, g1x, g1y, g1z);
    float gux = dsp0 * g0x + dsp1 * g1x;
    float guy = dsp0 * g0y + dsp1 * g1y;
    float guz = dsp0 * g0z + dsp1 * g1z;
    float gr = s0 * drp0 + s1v * drp1;
    float dgu = gux * x + guy * y + guz * z;
    float gvx = gr * x + inv_r * (gux - dgu * x);
    float gvy = gr * y + inv_r * (guy - dgu * y);
    float gvz = gr * z + inv_r * (guz - dgu * z);
    atomicAdd(&forces[snd * 3 + 0], gvx);
    atomicAdd(&forces[snd * 3 + 1], gvy);
    atomicAdd(&forces[snd * 3 + 2], gvz);
    atomicAdd(&forces[rcv * 3 + 0], -gvx);
    atomicAdd(&forces[rcv * 3 + 1], -gvy);
    atomicAdd(&forces[rcv * 3 + 2], -gvz);
}

// -------------------- node GEMM v3: all-LDS inner loop --------------------
#define GEMM_BLOCKS 512
template <bool WITH_EPI>
__global__ __launch_bounds__(256, 2) void node_gemm(const float* __restrict__ A,
                                                    const float* __restrict__ B,
                                                    const float* __restrict__ attrs,
                                                    const float* __restrict__ Wskip,
                                                    const float* __restrict__ wread,
                                                    float* __restrict__ C,
                                                    float* __restrict__ node_e) {
    __shared__ float sb[FF][FF];   // 64 KB
    __shared__ float sa[32][FF];   // 16 KB
    int t = threadIdx.x;
#pragma unroll
    for (int j = 0; j < 16; j++) {
        int flat4 = j * 256 + t;
        int row = flat4 >> 5;
        int col = (flat4 & 31) * 4;
        *(float4*)&sb[row][col] = *(const float4*)&B[row * FF + col];
    }

    int g = t >> 5;
    int f0 = (t & 31) * 4;
    const int NTILES = (NN + 31) / 32;

    for (int tile = blockIdx.x; tile < NTILES; tile += GEMM_BLOCKS) {
        __syncthreads();
#pragma unroll
        for (int j = 0; j < 4; j++) {
            int flat4 = j * 256 + t;
            int row = flat4 >> 5;
            int col = (flat4 & 31) * 4;
            int n = tile * 32 + row;
            float4 v = make_float4(0.f, 0.f, 0.f, 0.f);
            if (n < NN) v = *(const float4*)&A[(size_t)n * FF + col];
            *(float4*)&sa[row][col] = v;
        }
        __syncthreads();

        float acc[4][4];
#pragma unroll
        for (int i = 0; i < 4; i++)
#pragma unroll
            for (int j = 0; j < 4; j++) acc[i][j] = 0.f;

        for (int kk = 0; kk < FF; kk += 4) {
            float4 bv0 = *(const float4*)&sb[kk + 0][f0];
            float4 bv1 = *(const float4*)&sb[kk + 1][f0];
            float4 bv2 = *(const float4*)&sb[kk + 2][f0];
            float4 bv3 = *(const float4*)&sb[kk + 3][f0];
#pragma unroll
            for (int ni = 0; ni < 4; ni++) {
                float4 av = *(const float4*)&sa[g * 4 + ni][kk];
                acc[ni][0] += av.x * bv0.x + av.y * bv1.x + av.z * bv2.x + av.w * bv3.x;
                acc[ni][1] += av.x * bv0.y + av.y * bv1.y + av.z * bv2.y + av.w * bv3.y;
                acc[ni][2] += av.x * bv0.z + av.y * bv1.z + av.z * bv2.z + av.w * bv3.z;
                acc[ni][3] += av.x * bv0.w + av.y * bv1.w + av.z * bv2.w + av.w * bv3.w;
            }
        }

#pragma unroll
        for (int ni = 0; ni < 4; ni++) {
            int n = tile * 32 + g * 4 + ni;
            bool valid = (n < NN);
            if (WITH_EPI) {
#pragma unroll
                for (int a = 0; a < 10; a++) {
                    float att = valid ? attrs[n * 10 + a] : 0.f;
                    float4 wk = *(const float4*)&Wskip[a * FF + f0];
                    acc[ni][0] += att * wk.x;
                    acc[ni][1] += att * wk.y;
                    acc[ni][2] += att * wk.z;
                    acc[ni][3] += att * wk.w;
                }
            }
            if (valid) {
                float4 out;
                out.x = acc[ni][0]; out.y = acc[ni][1];
                out.z = acc[ni][2]; out.w = acc[ni][3];
                *(float4*)&C[(size_t)n * FF + f0] = out;
            }
            if (WITH_EPI) {
                float4 wv = *(const float4*)&wread[f0];
                float p = acc[ni][0] * wv.x + acc[ni][1] * wv.y
                        + acc[ni][2] * wv.z + acc[ni][3] * wv.w;
#pragma unroll
                for (int o = 16; o > 0; o >>= 1) p += __shfl_xor(p, o);
                if (valid && (t & 31) == 0) node_e[n] = p;
            }
        }
    }
}

// -------------------- energy reduction --------------------
#define ERED_BLOCKS 512
__global__ __launch_bounds__(256) void energy_kernel(const float* __restrict__ node_e,
                                                     const float* __restrict__ agg,
                                                     const float* __restrict__ attrs,
                                                     const float* __restrict__ a1,
                                                     const float* __restrict__ askip,
                                                     const int* __restrict__ batch,
                                                     float* __restrict__ energy) {
    __shared__ float eacc[GG];
    int t = threadIdx.x;
    if (t < GG) eacc[t] = 0.f;
    __syncthreads();

    int w = t >> 6;
    int lane = t & 63;
    for (int n = blockIdx.x * 4 + w; n < NN; n += ERED_BLOCKS * 4) {
        float p = agg[(size_t)n * FF + lane] * a1[lane]
                + agg[(size_t)n * FF + lane + 64] * a1[lane + 64];
        if (lane < 10) p += attrs[n * 10 + lane] * askip[lane];
        if (lane == 0) p += node_e[n];
#pragma unroll
        for (int o = 32; o > 0; o >>= 1) p += __shfl_xor(p, o);
        if (lane == 0) atomicAdd(&eacc[batch[n]], p);
    }
    __syncthreads();
    if (t < GG && eacc[t] != 0.f) atomicAdd(&energy[t], eacc[t]);
}

// -------------------- small prep kernels --------------------

__global__ __launch_bounds__(128) void a1_kernel(const float* __restrict__ Wout1,
                                                 const float* __restrict__ wread1,
                                                 const float* __restrict__ Wskip1,
                                                 const float* __restrict__ ae,
                                                 float* __restrict__ a1,
                                                 float* __restrict__ askip) {
    int f = threadIdx.x;
    float s = 0.f;
    for (int k = 0; k < FF; k++) s += Wout1[f * FF + k] * wread1[k];
    a1[f] = s;
    if (f < 10) {
        float t = 0.f;
        for (int k = 0; k < FF; k++) t += Wskip1[f * FF + k] * wread1[k];
        askip[f] = t + ae[f];
    }
}

__global__ __launch_bounds__(256) void transpose_kernel(const float* __restrict__ Wout0,
                                                        float* __restrict__ WoT) {
    int idx = blockIdx.x * 256 + threadIdx.x;
    int f = idx & 127;
    int k = idx >> 7;
    WoT[k * FF + f] = Wout0[f * FF + k];
}

// -------------------- launch --------------------

extern "C" void kernel_launch(void* const* d_in, const int* in_sizes, int n_in,
                              void* d_out, int out_size, void* d_ws, size_t ws_size,
                              hipStream_t stream) {
    const float* pos    = (const float*)d_in[0];
    const float* attrs  = (const float*)d_in[1];
    const float* shifts = (const float*)d_in[2];
    const int*   ei     = (const int*)d_in[3];
    const int*   batch  = (const int*)d_in[4];
    const float* W_emb  = (const float*)d_in[6];
    const float* ae     = (const float*)d_in[7];
    const float* W_r    = (const float*)d_in[8];   // (2,8,F)
    const float* w_sh   = (const float*)d_in[9];   // (2,16)
    const float* W_out  = (const float*)d_in[10];  // (2,F,F)
    const float* W_skip = (const float*)d_in[11];  // (2,10,F)
    const float* w_read = (const float*)d_in[12];  // (2,F)

    float* energy = (float*)d_out;
    float* forces = energy + GG;

    float* ws  = (float*)d_ws;
    float* h0  = ws;                     // N*F
    float* h1  = h0 + (size_t)NN * FF;   // N*F
    float* agg = h1 + (size_t)NN * FF;   // N*F (reused as b0)
    float* gh  = agg + (size_t)NN * FF;  // N*F
    float* geo = gh + (size_t)NN * FF;   // 22*EE
    float* a1  = geo + (size_t)22 * EE;  // F
    float* askip = a1 + FF;              // 16
    float* WoT = askip + 16;             // F*F
    float* node_e = WoT + FF * FF;       // N

    int* cnt  = (int*)(node_e + NN);     // 2*NN
    int* cur  = cnt + 2 * NN;            // 2*NN
    int* off  = cur + 2 * NN;            // 2*(NN+1)
    int* perm = off + 2 * (NN + 1);      // 2*EE
    const int* off_rcv  = off;
    const int* off_snd  = off + (NN + 1);
    const int* perm_rcv = perm;
    const int* perm_snd = perm + EE;

    const int edgeBlocks = (EE + 255) / 256;

    hipMemsetAsync(d_out, 0, (size_t)out_size * sizeof(float), stream);
    hipMemsetAsync(cnt, 0, (size_t)4 * NN * sizeof(int), stream);

    // CSR build
    count_kernel<<<edgeBlocks, 256, 0, stream>>>(ei, cnt);
    scan_kernel<<<2, 256, 0, stream>>>(cnt, off);
    fill_kernel<<<edgeBlocks, 256, 0, stream>>>(ei, off, cur, perm);

    // independent prep
    h0_kernel<<<NN / 2, 256, 0, stream>>>(attrs, W_emb, h0);
    edge_geom<<<edgeBlocks, 256, 0, stream>>>(pos, shifts, ei, w_sh, geo);
    a1_kernel<<<1, 128, 0, stream>>>(W_out + FF * FF, w_read + FF, W_skip + 10 * FF, ae,
                                     a1, askip);
    transpose_kernel<<<FF * FF / 256, 256, 0, stream>>>(W_out, WoT);

    // layer 0 forward
    fwd_csr<<<FEAT_BLOCKS, 256, 0, stream>>>(geo, geo + G_S0, ei, off_rcv, perm_rcv,
                                             h0, W_r, agg);
    node_gemm<true><<<GEMM_BLOCKS, 256, 0, stream>>>(agg, W_out, attrs, W_skip, w_read,
                                                     h1, node_e);

    // layer 1 forward
    fwd_csr<<<FEAT_BLOCKS, 256, 0, stream>>>(geo, geo + G_S1, ei, off_rcv, perm_rcv,
                                             h1, W_r + NBES * FF, agg);
    energy_kernel<<<ERED_BLOCKS, 256, 0, stream>>>(node_e, agg, attrs, a1, askip, batch,
                                                   energy);

    // layer 1 backward (gh, dsp1/drp1) — snd-CSR, register-resident
    bwd1_csr<<<FEAT_BLOCKS, 256, 0, stream>>>(geo, geo + G_S1, off_snd, perm_snd, h1,
                                              W_r + NBES * FF, a1, w_read, gh,
                                              geo + G_DSP1, geo + G_DRP1);
    // b0 = gh @ Wout0^T (into agg buffer)
    node_gemm<false><<<GEMM_BLOCKS, 256, 0, stream>>>(gh, WoT, nullptr, nullptr, nullptr,
                                                      agg, nullptr);
    // layer 0 backward (dsp0/drp0) — rcv-CSR
    bwd0_csr<<<FEAT_BLOCKS, 256, 0, stream>>>(geo, ei, off_rcv, perm_rcv, h0, W_r,
                                              agg, geo + G_DSP0, geo + G_DRP0);
    // forces for both layers
    force_kernel<<<edgeBlocks, 256, 0, stream>>>(pos, shifts, ei, w_sh, geo, forces);
}

// Round 7
// 1411.235 us; speedup vs baseline: 1.2525x; 1.2525x over previous
//
#include <hip/hip_runtime.h>

#define NN 50000
#define EE 800000
#define GG 64
#define FF 128
#define NBES 8
#define RMAXF 5.0f
#define PI_F 3.14159265358979323846f
#define RECW 20   // floats per edge geometry record

// spherical harmonic constants
#define S3  1.7320508075688772f
#define S5  2.23606797749979f
#define S15 3.872983346207417f
#define C1c 2.091650066335189f   // sqrt(35/8)
#define C2c 10.246950765959598f  // sqrt(105)
#define C3c 1.62018517460196f    // sqrt(21/8)
#define C4c 1.3228756555322954f  // sqrt(7)/2
#define C5c 5.123475382979799f   // sqrt(105)/2
#define CCB 0.6324555320336759f  // sqrt(2/5)

__device__ __forceinline__ float shc_s(float x, float y, float z, const float* __restrict__ w) {
    float x2 = x * x, y2 = y * y, z2 = z * z;
    return w[0]
        + w[1] * (S3 * x) + w[2] * (S3 * y) + w[3] * (S3 * z)
        + w[4] * (S15 * x * y) + w[5] * (S15 * y * z) + w[6] * (0.5f * S5 * (3.f * z2 - 1.f))
        + w[7] * (S15 * x * z) + w[8] * (0.5f * S15 * (x2 - y2))
        + w[9] * (C1c * y * (3.f * x2 - y2)) + w[10] * (C2c * x * y * z)
        + w[11] * (C3c * y * (5.f * z2 - 1.f)) + w[12] * (C4c * z * (5.f * z2 - 3.f))
        + w[13] * (C3c * x * (5.f * z2 - 1.f)) + w[14] * (C5c * z * (x2 - y2))
        + w[15] * (C1c * x * (x2 - 3.f * y2));
}

__device__ __forceinline__ void shc_grad(float x, float y, float z, const float* __restrict__ w,
                                         float& gx, float& gy, float& gz) {
    float x2 = x * x, y2 = y * y, z2 = z * z;
    gx = w[1] * S3 + w[4] * (S15 * y) + w[7] * (S15 * z) + w[8] * (S15 * x)
       + w[9] * (6.f * C1c * x * y) + w[10] * (C2c * y * z) + w[13] * (C3c * (5.f * z2 - 1.f))
       + w[14] * (2.f * C5c * x * z) + w[15] * (3.f * C1c * (x2 - y2));
    gy = w[2] * S3 + w[4] * (S15 * x) + w[5] * (S15 * z) - w[8] * (S15 * y)
       + w[9] * (3.f * C1c * (x2 - y2)) + w[10] * (C2c * x * z) + w[11] * (C3c * (5.f * z2 - 1.f))
       - w[14] * (2.f * C5c * y * z) - w[15] * (6.f * C1c * x * y);
    gz = w[3] * S3 + w[5] * (S15 * y) + w[6] * (3.f * S5 * z) + w[7] * (S15 * x)
       + w[10] * (C2c * x * y) + w[11] * (10.f * C3c * y * z) + w[12] * (C4c * (15.f * z2 - 3.f))
       + w[13] * (10.f * C3c * x * z) + w[14] * (C5c * (x2 - y2));
}

// -------------------- CSR build --------------------

__global__ __launch_bounds__(256) void count_kernel(const int* __restrict__ ei,
                                                    int* __restrict__ cnt) {
    int e = blockIdx.x * 256 + threadIdx.x;
    if (e >= EE) return;
    atomicAdd(&cnt[ei[EE + e]], 1);        // rcv counts
    atomicAdd(&cnt[NN + ei[e]], 1);        // snd counts
}

__global__ __launch_bounds__(256) void scan_kernel(const int* __restrict__ cnt,
                                                   int* __restrict__ off) {
    const int* c = cnt + (size_t)blockIdx.x * NN;
    int* o = off + (size_t)blockIdx.x * (NN + 1);
    __shared__ int wsum[4];
    __shared__ int carry_s;
    if (threadIdx.x == 0) carry_s = 0;
    __syncthreads();
    int lane = threadIdx.x & 63;
    int wid = threadIdx.x >> 6;
    for (int base = 0; base < NN; base += 256) {
        int i = base + threadIdx.x;
        int v = (i < NN) ? c[i] : 0;
        int x = v;
#pragma unroll
        for (int d = 1; d < 64; d <<= 1) {
            int y = __shfl_up(x, d);
            if (lane >= d) x += y;
        }
        if (lane == 63) wsum[wid] = x;
        __syncthreads();
        int pre = 0;
#pragma unroll
        for (int w = 0; w < 4; w++) if (w < wid) pre += wsum[w];
        int total = wsum[0] + wsum[1] + wsum[2] + wsum[3];
        int carry = carry_s;
        if (i < NN) o[i] = carry + pre + x - v;
        __syncthreads();
        if (threadIdx.x == 0) carry_s = carry + total;
        __syncthreads();
    }
    if (threadIdx.x == 0) o[NN] = carry_s;
}

__global__ __launch_bounds__(256) void fill_kernel(const int* __restrict__ ei,
                                                   const int* __restrict__ off,
                                                   int* __restrict__ cur,
                                                   int* __restrict__ perm) {
    int e = blockIdx.x * 256 + threadIdx.x;
    if (e >= EE) return;
    int snd = ei[e], rcv = ei[EE + e];
    int p0 = off[rcv] + atomicAdd(&cur[rcv], 1);
    perm[p0] = e;
    int p1 = off[(NN + 1) + snd] + atomicAdd(&cur[NN + snd], 1);
    perm[EE + p1] = e;
}

// -------------------- geometry (thread-per-edge) --------------------
// AoS record per edge: rec[e*20 + {0..7 eb, 8..15 db, 16 s0, 17 s1, 18..19 pad}]
__global__ __launch_bounds__(256) void edge_geom(const float* __restrict__ pos,
                                                 const float* __restrict__ shifts,
                                                 const int* __restrict__ ei,
                                                 const float* __restrict__ wsh,
                                                 float* __restrict__ rec,
                                                 float* __restrict__ s0a,
                                                 float* __restrict__ s1a) {
    int e = blockIdx.x * 256 + threadIdx.x;
    if (e >= EE) return;
    int snd = ei[e];
    int rcv = ei[EE + e];
    float vx = pos[rcv * 3 + 0] - pos[snd * 3 + 0] + shifts[e * 3 + 0];
    float vy = pos[rcv * 3 + 1] - pos[snd * 3 + 1] + shifts[e * 3 + 1];
    float vz = pos[rcv * 3 + 2] - pos[snd * 3 + 2] + shifts[e * 3 + 2];
    float r2 = vx * vx + vy * vy + vz * vz + 1e-12f;
    float r = sqrtf(r2);
    float inv_r = 1.0f / r;
    float x = vx * inv_r, y = vy * inv_r, z = vz * inv_r;
    float valid = (r < RMAXF) ? 1.f : 0.f;

    float s0 = shc_s(x, y, z, wsh);
    float s1v = shc_s(x, y, z, wsh + 16);
    s0a[e] = s0;
    s1a[e] = s1v;

    float u = r * (1.0f / RMAXF);
    float th = PI_F * u;
    float s1 = sinf(th), c1 = cosf(th);
    float u2 = u * u, u3 = u2 * u, u5 = u2 * u3, u6 = u3 * u3, u7 = u6 * u, u8 = u6 * u2;
    float env = (1.f - 28.f * u6 + 48.f * u7 - 21.f * u8) * valid;
    float denv = (-168.f * u5 + 336.f * u6 - 168.f * u7) * (1.0f / RMAXF) * valid;
    float sk = s1, skm = 0.f, ck = c1, ckm = 1.f;
    float tc = 2.f * c1;
    float ebv[NBES], dbv[NBES];
#pragma unroll
    for (int k = 1; k <= NBES; k++) {
        float b = CCB * sk * inv_r;
        ebv[k - 1] = b * env;
        dbv[k - 1] = CCB * (((float)k * PI_F * (1.0f / RMAXF)) * ck * inv_r
                            - sk * inv_r * inv_r) * env
                     + b * denv;
        float sn = tc * sk - skm; skm = sk; sk = sn;
        float cn = tc * ck - ckm; ckm = ck; ck = cn;
    }
    float* rc = rec + (size_t)e * RECW;
    *(float4*)&rc[0]  = make_float4(ebv[0], ebv[1], ebv[2], ebv[3]);
    *(float4*)&rc[4]  = make_float4(ebv[4], ebv[5], ebv[6], ebv[7]);
    *(float4*)&rc[8]  = make_float4(dbv[0], dbv[1], dbv[2], dbv[3]);
    *(float4*)&rc[12] = make_float4(dbv[4], dbv[5], dbv[6], dbv[7]);
    *(float4*)&rc[16] = make_float4(s0, s1v, 0.f, 0.f);
}

// -------------------- node prep --------------------

__global__ __launch_bounds__(256) void h0_kernel(const float* __restrict__ attrs,
                                                 const float* __restrict__ W_emb,
                                                 float* __restrict__ h0) {
    int sub = threadIdx.x >> 7;
    int f = threadIdx.x & 127;
    int n = blockIdx.x * 2 + sub;
    float acc = 0.f;
#pragma unroll
    for (int a = 0; a < 10; a++) acc += attrs[n * 10 + a] * W_emb[a * FF + f];
    h0[n * FF + f] = acc;
}

// -------------------- CSR edge kernels (wave-per-node, grid-stride) --------------------

#define FEAT_BLOCKS 2048

// agg[n][f] = sum_{e: rcv=n} h_src[snd_e][f] * R_e[f] * s_e   (no atomics)
__global__ __launch_bounds__(256) void fwd_csr(const float* __restrict__ rec,
                                               int sofs,
                                               const int* __restrict__ ei,
                                               const int* __restrict__ off_rcv,
                                               const int* __restrict__ perm_rcv,
                                               const float* __restrict__ h_src,
                                               const float* __restrict__ Wr,
                                               float* __restrict__ agg) {
    int wv = (blockIdx.x * 256 + threadIdx.x) >> 6;
    int lane = threadIdx.x & 63;
    int nwaves = FEAT_BLOCKS * 4;
    int f0 = lane, f1 = lane + 64;
    float wr0[NBES], wr1[NBES];
#pragma unroll
    for (int k = 0; k < NBES; k++) { wr0[k] = Wr[k * FF + f0]; wr1[k] = Wr[k * FF + f1]; }

    for (int n = wv; n < NN; n += nwaves) {
        int beg = off_rcv[n], end = off_rcv[n + 1];
        float acc0 = 0.f, acc1 = 0.f;
        for (int j = beg; j < end; j++) {
            int e = perm_rcv[j];
            int snd = ei[e];
            const float* rc = rec + (size_t)e * RECW;
            float ebv[NBES];
            *(float4*)&ebv[0] = *(const float4*)&rc[0];
            *(float4*)&ebv[4] = *(const float4*)&rc[4];
            float s = rc[sofs];
            float R0 = 0.f, R1 = 0.f;
#pragma unroll
            for (int k = 0; k < NBES; k++) {
                R0 += ebv[k] * wr0[k];
                R1 += ebv[k] * wr1[k];
            }
            acc0 += h_src[(size_t)snd * FF + f0] * R0 * s;
            acc1 += h_src[(size_t)snd * FF + f1] * R1 * s;
        }
        agg[(size_t)n * FF + f0] = acc0;
        agg[(size_t)n * FF + f1] = acc1;
    }
}

// layer-1 backward over snd-CSR: h1[n] and gh[n] in registers; no gather, no atomics.
__global__ __launch_bounds__(256) void bwd1_csr(const float* __restrict__ rec,
                                                const int* __restrict__ off_snd,
                                                const int* __restrict__ perm_snd,
                                                const float* __restrict__ h1,
                                                const float* __restrict__ Wr1,
                                                const float* __restrict__ a1,
                                                const float* __restrict__ wread0,
                                                float* __restrict__ gh,
                                                float* __restrict__ dsp_out,
                                                float* __restrict__ drp_out) {
    int wv = (blockIdx.x * 256 + threadIdx.x) >> 6;
    int lane = threadIdx.x & 63;
    int nwaves = FEAT_BLOCKS * 4;
    int f0 = lane, f1 = lane + 64;
    float wr0[NBES], wr1[NBES];
#pragma unroll
    for (int k = 0; k < NBES; k++) { wr0[k] = Wr1[k * FF + f0]; wr1[k] = Wr1[k * FF + f1]; }
    float dm0 = a1[f0], dm1 = a1[f1];
    float w0 = wread0[f0], w1 = wread0[f1];

    for (int n = wv; n < NN; n += nwaves) {
        int beg = off_snd[n], end = off_snd[n + 1];
        float hh0 = h1[(size_t)n * FF + f0];
        float hh1 = h1[(size_t)n * FF + f1];
        float dh0 = dm0 * hh0, dh1 = dm1 * hh1;
        float g0 = 0.f, g1 = 0.f;
        for (int j = beg; j < end; j++) {
            int e = perm_snd[j];
            const float* rc = rec + (size_t)e * RECW;
            float ebv[NBES], dbv[NBES];
            *(float4*)&ebv[0] = *(const float4*)&rc[0];
            *(float4*)&ebv[4] = *(const float4*)&rc[4];
            *(float4*)&dbv[0] = *(const float4*)&rc[8];
            *(float4*)&dbv[4] = *(const float4*)&rc[12];
            float s = rc[17];
            float R0 = 0.f, R1 = 0.f, Rd0 = 0.f, Rd1 = 0.f;
#pragma unroll
            for (int k = 0; k < NBES; k++) {
                R0 += ebv[k] * wr0[k];
                R1 += ebv[k] * wr1[k];
                Rd0 += dbv[k] * wr0[k];
                Rd1 += dbv[k] * wr1[k];
            }
            float dsp = dh0 * R0 + dh1 * R1;
            float drp = dh0 * Rd0 + dh1 * Rd1;
#pragma unroll
            for (int o = 32; o > 0; o >>= 1) {
                dsp += __shfl_xor(dsp, o);
                drp += __shfl_xor(drp, o);
            }
            if (lane == 0) { dsp_out[e] = dsp; drp_out[e] = drp; }
            g0 += dm0 * R0 * s;
            g1 += dm1 * R1 * s;
        }
        gh[(size_t)n * FF + f0] = w0 + g0;
        gh[(size_t)n * FF + f1] = w1 + g1;
    }
}

// layer-0 backward over rcv-CSR: b0[n] in registers; gather h0[snd].
__global__ __launch_bounds__(256) void bwd0_csr(const float* __restrict__ rec,
                                                const int* __restrict__ ei,
                                                const int* __restrict__ off_rcv,
                                                const int* __restrict__ perm_rcv,
                                                const float* __restrict__ h0,
                                                const float* __restrict__ Wr0,
                                                const float* __restrict__ b0,
                                                float* __restrict__ dsp_out,
                                                float* __restrict__ drp_out) {
    int wv = (blockIdx.x * 256 + threadIdx.x) >> 6;
    int lane = threadIdx.x & 63;
    int nwaves = FEAT_BLOCKS * 4;
    int f0 = lane, f1 = lane + 64;
    float wr0[NBES], wr1[NBES];
#pragma unroll
    for (int k = 0; k < NBES; k++) { wr0[k] = Wr0[k * FF + f0]; wr1[k] = Wr0[k * FF + f1]; }

    for (int n = wv; n < NN; n += nwaves) {
        int beg = off_rcv[n], end = off_rcv[n + 1];
        float dm0 = b0[(size_t)n * FF + f0];
        float dm1 = b0[(size_t)n * FF + f1];
        for (int j = beg; j < end; j++) {
            int e = perm_rcv[j];
            int snd = ei[e];
            const float* rc = rec + (size_t)e * RECW;
            float ebv[NBES], dbv[NBES];
            *(float4*)&ebv[0] = *(const float4*)&rc[0];
            *(float4*)&ebv[4] = *(const float4*)&rc[4];
            *(float4*)&dbv[0] = *(const float4*)&rc[8];
            *(float4*)&dbv[4] = *(const float4*)&rc[12];
            float R0 = 0.f, R1 = 0.f, Rd0 = 0.f, Rd1 = 0.f;
#pragma unroll
            for (int k = 0; k < NBES; k++) {
                R0 += ebv[k] * wr0[k];
                R1 += ebv[k] * wr1[k];
                Rd0 += dbv[k] * wr0[k];
                Rd1 += dbv[k] * wr1[k];
            }
            float dh0 = dm0 * h0[(size_t)snd * FF + f0];
            float dh1 = dm1 * h0[(size_t)snd * FF + f1];
            float dsp = dh0 * R0 + dh1 * R1;
            float drp = dh0 * Rd0 + dh1 * Rd1;
#pragma unroll
            for (int o = 32; o > 0; o >>= 1) {
                dsp += __shfl_xor(dsp, o);
                drp += __shfl_xor(drp, o);
            }
            if (lane == 0) { dsp_out[e] = dsp; drp_out[e] = drp; }
        }
    }
}

// -------------------- force finalize (thread-per-edge, both layers) --------------------

__global__ __launch_bounds__(256) void force_kernel(const float* __restrict__ pos,
                                                    const float* __restrict__ shifts,
                                                    const int* __restrict__ ei,
                                                    const float* __restrict__ wsh,
                                                    const float* __restrict__ s0a,
                                                    const float* __restrict__ s1a,
                                                    const float* __restrict__ dsp0a,
                                                    const float* __restrict__ drp0a,
                                                    const float* __restrict__ dsp1a,
                                                    const float* __restrict__ drp1a,
                                                    float* __restrict__ forces) {
    int e = blockIdx.x * 256 + threadIdx.x;
    if (e >= EE) return;
    int snd = ei[e];
    int rcv = ei[EE + e];
    float vx = pos[rcv * 3 + 0] - pos[snd * 3 + 0] + shifts[e * 3 + 0];
    float vy = pos[rcv * 3 + 1] - pos[snd * 3 + 1] + shifts[e * 3 + 1];
    float vz = pos[rcv * 3 + 2] - pos[snd * 3 + 2] + shifts[e * 3 + 2];
    float r2 = vx * vx + vy * vy + vz * vz + 1e-12f;
    float r = sqrtf(r2);
    float inv_r = 1.0f / r;
    float x = vx * inv_r, y = vy * inv_r, z = vz * inv_r;

    float dsp0 = dsp0a[e], drp0 = drp0a[e];
    float dsp1 = dsp1a[e], drp1 = drp1a[e];
    float s0 = s0a[e], s1v = s1a[e];

    float g0x, g0y, g0z, g1x, g1y, g1z;
    shc_grad(x, y, z, wsh, g0x, g0y, g0z);
    shc_grad(x, y, z, wsh + 16, g1x, g1y, g1z);
    float gux = dsp0 * g0x + dsp1 * g1x;
    float guy = dsp0 * g0y + dsp1 * g1y;
    float guz = dsp0 * g0z + dsp1 * g1z;
    float gr = s0 * drp0 + s1v * drp1;
    float dgu = gux * x + guy * y + guz * z;
    float gvx = gr * x + inv_r * (gux - dgu * x);
    float gvy = gr * y + inv_r * (guy - dgu * y);
    float gvz = gr * z + inv_r * (guz - dgu * z);
    atomicAdd(&forces[snd * 3 + 0], gvx);
    atomicAdd(&forces[snd * 3 + 1], gvy);
    atomicAdd(&forces[snd * 3 + 2], gvz);
    atomicAdd(&forces[rcv * 3 + 0], -gvx);
    atomicAdd(&forces[rcv * 3 + 1], -gvy);
    atomicAdd(&forces[rcv * 3 + 2], -gvz);
}

// -------------------- node GEMM v3: all-LDS inner loop --------------------
#define GEMM_BLOCKS 512
template <bool WITH_EPI>
__global__ __launch_bounds__(256, 2) void node_gemm(const float* __restrict__ A,
                                                    const float* __restrict__ B,
                                                    const float* __restrict__ attrs,
                                                    const float* __restrict__ Wskip,
                                                    const float* __restrict__ wread,
                                                    float* __restrict__ C,
                                                    float* __restrict__ node_e) {
    __shared__ float sb[FF][FF];   // 64 KB
    __shared__ float sa[32][FF];   // 16 KB
    int t = threadIdx.x;
#pragma unroll
    for (int j = 0; j < 16; j++) {
        int flat4 = j * 256 + t;
        int row = flat4 >> 5;
        int col = (flat4 & 31) * 4;
        *(float4*)&sb[row][col] = *(const float4*)&B[row * FF + col];
    }

    int g = t >> 5;
    int f0 = (t & 31) * 4;
    const int NTILES = (NN + 31) / 32;

    for (int tile = blockIdx.x; tile < NTILES; tile += GEMM_BLOCKS) {
        __syncthreads();
#pragma unroll
        for (int j = 0; j < 4; j++) {
            int flat4 = j * 256 + t;
            int row = flat4 >> 5;
            int col = (flat4 & 31) * 4;
            int n = tile * 32 + row;
            float4 v = make_float4(0.f, 0.f, 0.f, 0.f);
            if (n < NN) v = *(const float4*)&A[(size_t)n * FF + col];
            *(float4*)&sa[row][col] = v;
        }
        __syncthreads();

        float acc[4][4];
#pragma unroll
        for (int i = 0; i < 4; i++)
#pragma unroll
            for (int j = 0; j < 4; j++) acc[i][j] = 0.f;

        for (int kk = 0; kk < FF; kk += 4) {
            float4 bv0 = *(const float4*)&sb[kk + 0][f0];
            float4 bv1 = *(const float4*)&sb[kk + 1][f0];
            float4 bv2 = *(const float4*)&sb[kk + 2][f0];
            float4 bv3 = *(const float4*)&sb[kk + 3][f0];
#pragma unroll
            for (int ni = 0; ni < 4; ni++) {
                float4 av = *(const float4*)&sa[g * 4 + ni][kk];
                acc[ni][0] += av.x * bv0.x + av.y * bv1.x + av.z * bv2.x + av.w * bv3.x;
                acc[ni][1] += av.x * bv0.y + av.y * bv1.y + av.z * bv2.y + av.w * bv3.y;
                acc[ni][2] += av.x * bv0.z + av.y * bv1.z + av.z * bv2.z + av.w * bv3.z;
                acc[ni][3] += av.x * bv0.w + av.y * bv1.w + av.z * bv2.w + av.w * bv3.w;
            }
        }

#pragma unroll
        for (int ni = 0; ni < 4; ni++) {
            int n = tile * 32 + g * 4 + ni;
            bool valid = (n < NN);
            if (WITH_EPI) {
#pragma unroll
                for (int a = 0; a < 10; a++) {
                    float att = valid ? attrs[n * 10 + a] : 0.f;
                    float4 wk = *(const float4*)&Wskip[a * FF + f0];
                    acc[ni][0] += att * wk.x;
                    acc[ni][1] += att * wk.y;
                    acc[ni][2] += att * wk.z;
                    acc[ni][3] += att * wk.w;
                }
            }
            if (valid) {
                float4 out;
                out.x = acc[ni][0]; out.y = acc[ni][1];
                out.z = acc[ni][2]; out.w = acc[ni][3];
                *(float4*)&C[(size_t)n * FF + f0] = out;
            }
            if (WITH_EPI) {
                float4 wv = *(const float4*)&wread[f0];
                float p = acc[ni][0] * wv.x + acc[ni][1] * wv.y
                        + acc[ni][2] * wv.z + acc[ni][3] * wv.w;
#pragma unroll
                for (int o = 16; o > 0; o >>= 1) p += __shfl_xor(p, o);
                if (valid && (t & 31) == 0) node_e[n] = p;
            }
        }
    }
}

// -------------------- energy reduction --------------------
#define ERED_BLOCKS 512
__global__ __launch_bounds__(256) void energy_kernel(const float* __restrict__ node_e,
                                                     const float* __restrict__ agg,
                                                     const float* __restrict__ attrs,
                                                     const float* __restrict__ a1,
                                                     const float* __restrict__ askip,
                                                     const int* __restrict__ batch,
                                                     float* __restrict__ energy) {
    __shared__ float eacc[GG];
    int t = threadIdx.x;
    if (t < GG) eacc[t] = 0.f;
    __syncthreads();

    int w = t >> 6;
    int lane = t & 63;
    for (int n = blockIdx.x * 4 + w; n < NN; n += ERED_BLOCKS * 4) {
        float p = agg[(size_t)n * FF + lane] * a1[lane]
                + agg[(size_t)n * FF + lane + 64] * a1[lane + 64];
        if (lane < 10) p += attrs[n * 10 + lane] * askip[lane];
        if (lane == 0) p += node_e[n];
#pragma unroll
        for (int o = 32; o > 0; o >>= 1) p += __shfl_xor(p, o);
        if (lane == 0) atomicAdd(&eacc[batch[n]], p);
    }
    __syncthreads();
    if (t < GG && eacc[t] != 0.f) atomicAdd(&energy[t], eacc[t]);
}

// -------------------- small prep kernels --------------------

__global__ __launch_bounds__(128) void a1_kernel(const float* __restrict__ Wout1,
                                                 const float* __restrict__ wread1,
                                                 const float* __restrict__ Wskip1,
                                                 const float* __restrict__ ae,
                                                 float* __restrict__ a1,
                                                 float* __restrict__ askip) {
    int f = threadIdx.x;
    float s = 0.f;
    for (int k = 0; k < FF; k++) s += Wout1[f * FF + k] * wread1[k];
    a1[f] = s;
    if (f < 10) {
        float t = 0.f;
        for (int k = 0; k < FF; k++) t += Wskip1[f * FF + k] * wread1[k];
        askip[f] = t + ae[f];
    }
}

__global__ __launch_bounds__(256) void transpose_kernel(const float* __restrict__ Wout0,
                                                        float* __restrict__ WoT) {
    int idx = blockIdx.x * 256 + threadIdx.x;
    int f = idx & 127;
    int k = idx >> 7;
    WoT[k * FF + f] = Wout0[f * FF + k];
}

// -------------------- launch --------------------

extern "C" void kernel_launch(void* const* d_in, const int* in_sizes, int n_in,
                              void* d_out, int out_size, void* d_ws, size_t ws_size,
                              hipStream_t stream) {
    const float* pos    = (const float*)d_in[0];
    const float* attrs  = (const float*)d_in[1];
    const float* shifts = (const float*)d_in[2];
    const int*   ei     = (const int*)d_in[3];
    const int*   batch  = (const int*)d_in[4];
    const float* W_emb  = (const float*)d_in[6];
    const float* ae     = (const float*)d_in[7];
    const float* W_r    = (const float*)d_in[8];   // (2,8,F)
    const float* w_sh   = (const float*)d_in[9];   // (2,16)
    const float* W_out  = (const float*)d_in[10];  // (2,F,F)
    const float* W_skip = (const float*)d_in[11];  // (2,10,F)
    const float* w_read = (const float*)d_in[12];  // (2,F)

    float* energy = (float*)d_out;
    float* forces = energy + GG;

    float* ws  = (float*)d_ws;
    float* h0  = ws;                      // N*F
    float* h1  = h0 + (size_t)NN * FF;    // N*F
    float* agg = h1 + (size_t)NN * FF;    // N*F (reused as b0)
    float* gh  = agg + (size_t)NN * FF;   // N*F
    float* rec = gh + (size_t)NN * FF;    // 20*EE (AoS geometry)
    float* s0a = rec + (size_t)RECW * EE; // EE
    float* s1a = s0a + EE;                // EE
    float* dsp0 = s1a + EE;               // EE
    float* drp0 = dsp0 + EE;              // EE
    float* dsp1 = drp0 + EE;              // EE
    float* drp1 = dsp1 + EE;              // EE
    float* a1  = drp1 + EE;               // F
    float* askip = a1 + FF;               // 16
    float* WoT = askip + 16;              // F*F
    float* node_e = WoT + FF * FF;        // N

    int* cnt  = (int*)(node_e + NN);      // 2*NN
    int* cur  = cnt + 2 * NN;             // 2*NN
    int* off  = cur + 2 * NN;             // 2*(NN+1)
    int* perm = off + 2 * (NN + 1);       // 2*EE
    const int* off_rcv  = off;
    const int* off_snd  = off + (NN + 1);
    const int* perm_rcv = perm;
    const int* perm_snd = perm + EE;

    const int edgeBlocks = (EE + 255) / 256;

    hipMemsetAsync(d_out, 0, (size_t)out_size * sizeof(float), stream);
    hipMemsetAsync(cnt, 0, (size_t)4 * NN * sizeof(int), stream);

    // CSR build
    count_kernel<<<edgeBlocks, 256, 0, stream>>>(ei, cnt);
    scan_kernel<<<2, 256, 0, stream>>>(cnt, off);
    fill_kernel<<<edgeBlocks, 256, 0, stream>>>(ei, off, cur, perm);

    // independent prep
    h0_kernel<<<NN / 2, 256, 0, stream>>>(attrs, W_emb, h0);
    edge_geom<<<edgeBlocks, 256, 0, stream>>>(pos, shifts, ei, w_sh, rec, s0a, s1a);
    a1_kernel<<<1, 128, 0, stream>>>(W_out + FF * FF, w_read + FF, W_skip + 10 * FF, ae,
                                     a1, askip);
    transpose_kernel<<<FF * FF / 256, 256, 0, stream>>>(W_out, WoT);

    // layer 0 forward
    fwd_csr<<<FEAT_BLOCKS, 256, 0, stream>>>(rec, 16, ei, off_rcv, perm_rcv,
                                             h0, W_r, agg);
    node_gemm<true><<<GEMM_BLOCKS, 256, 0, stream>>>(agg, W_out, attrs, W_skip, w_read,
                                                     h1, node_e);

    // layer 1 forward
    fwd_csr<<<FEAT_BLOCKS, 256, 0, stream>>>(rec, 17, ei, off_rcv, perm_rcv,
                                             h1, W_r + NBES * FF, agg);
    energy_kernel<<<ERED_BLOCKS, 256, 0, stream>>>(node_e, agg, attrs, a1, askip, batch,
                                                   energy);

    // layer 1 backward (gh, dsp1/drp1) — snd-CSR, register-resident
    bwd1_csr<<<FEAT_BLOCKS, 256, 0, stream>>>(rec, off_snd, perm_snd, h1,
                                              W_r + NBES * FF, a1, w_read, gh,
                                              dsp1, drp1);
    // b0 = gh @ Wout0^T (into agg buffer)
    node_gemm<false><<<GEMM_BLOCKS, 256, 0, stream>>>(gh, WoT, nullptr, nullptr, nullptr,
                                                      agg, nullptr);
    // layer 0 backward (dsp0/drp0) — rcv-CSR
    bwd0_csr<<<FEAT_BLOCKS, 256, 0, stream>>>(rec, ei, off_rcv, perm_rcv, h0, W_r,
                                              agg, dsp0, drp0);
    // forces for both layers
    force_kernel<<<edgeBlocks, 256, 0, stream>>>(pos, shifts, ei, w_sh, s0a, s1a,
                                                 dsp0, drp0, dsp1, drp1, forces);
}

// Round 8
// 1038.243 us; speedup vs baseline: 1.7024x; 1.3593x over previous
//
#include <hip/hip_runtime.h>

#define NN 50000
#define EE 800000
#define GG 64
#define FF 128
#define NBES 8
#define RECW 24   // floats per edge record: eb[8], db[8], s0, s1, x, y, z, inv_r, snd, rcv
#define RMAXF 5.0f
#define PI_F 3.14159265358979323846f

// spherical harmonic constants
#define S3  1.7320508075688772f
#define S5  2.23606797749979f
#define S15 3.872983346207417f
#define C1c 2.091650066335189f   // sqrt(35/8)
#define C2c 10.246950765959598f  // sqrt(105)
#define C3c 1.62018517460196f    // sqrt(21/8)
#define C4c 1.3228756555322954f  // sqrt(7)/2
#define C5c 5.123475382979799f   // sqrt(105)/2
#define CCB 0.6324555320336759f  // sqrt(2/5)

__device__ __forceinline__ float shc_s(float x, float y, float z, const float* __restrict__ w) {
    float x2 = x * x, y2 = y * y, z2 = z * z;
    return w[0]
        + w[1] * (S3 * x) + w[2] * (S3 * y) + w[3] * (S3 * z)
        + w[4] * (S15 * x * y) + w[5] * (S15 * y * z) + w[6] * (0.5f * S5 * (3.f * z2 - 1.f))
        + w[7] * (S15 * x * z) + w[8] * (0.5f * S15 * (x2 - y2))
        + w[9] * (C1c * y * (3.f * x2 - y2)) + w[10] * (C2c * x * y * z)
        + w[11] * (C3c * y * (5.f * z2 - 1.f)) + w[12] * (C4c * z * (5.f * z2 - 3.f))
        + w[13] * (C3c * x * (5.f * z2 - 1.f)) + w[14] * (C5c * z * (x2 - y2))
        + w[15] * (C1c * x * (x2 - 3.f * y2));
}

__device__ __forceinline__ void shc_grad(float x, float y, float z, const float* __restrict__ w,
                                         float& gx, float& gy, float& gz) {
    float x2 = x * x, y2 = y * y, z2 = z * z;
    gx = w[1] * S3 + w[4] * (S15 * y) + w[7] * (S15 * z) + w[8] * (S15 * x)
       + w[9] * (6.f * C1c * x * y) + w[10] * (C2c * y * z) + w[13] * (C3c * (5.f * z2 - 1.f))
       + w[14] * (2.f * C5c * x * z) + w[15] * (3.f * C1c * (x2 - y2));
    gy = w[2] * S3 + w[4] * (S15 * x) + w[5] * (S15 * z) - w[8] * (S15 * y)
       + w[9] * (3.f * C1c * (x2 - y2)) + w[10] * (C2c * x * z) + w[11] * (C3c * (5.f * z2 - 1.f))
       - w[14] * (2.f * C5c * y * z) - w[15] * (6.f * C1c * x * y);
    gz = w[3] * S3 + w[5] * (S15 * y) + w[6] * (3.f * S5 * z) + w[7] * (S15 * x)
       + w[10] * (C2c * x * y) + w[11] * (10.f * C3c * y * z) + w[12] * (C4c * (15.f * z2 - 3.f))
       + w[13] * (10.f * C3c * x * z) + w[14] * (C5c * (x2 - y2));
}

// -------------------- CSR build (rcv only) --------------------

__global__ __launch_bounds__(256) void count_kernel(const int* __restrict__ ei,
                                                    int* __restrict__ cnt) {
    int e = blockIdx.x * 256 + threadIdx.x;
    if (e >= EE) return;
    atomicAdd(&cnt[ei[EE + e]], 1);
}

// single block, chunked scan of cnt[NN] -> off[NN+1]
__global__ __launch_bounds__(256) void scan_kernel(const int* __restrict__ cnt,
                                                   int* __restrict__ off) {
    __shared__ int wsum[4];
    __shared__ int carry_s;
    if (threadIdx.x == 0) carry_s = 0;
    __syncthreads();
    int lane = threadIdx.x & 63;
    int wid = threadIdx.x >> 6;
    for (int base = 0; base < NN; base += 256) {
        int i = base + threadIdx.x;
        int v = (i < NN) ? cnt[i] : 0;
        int x = v;
#pragma unroll
        for (int d = 1; d < 64; d <<= 1) {
            int y = __shfl_up(x, d);
            if (lane >= d) x += y;
        }
        if (lane == 63) wsum[wid] = x;
        __syncthreads();
        int pre = 0;
#pragma unroll
        for (int w = 0; w < 4; w++) if (w < wid) pre += wsum[w];
        int total = wsum[0] + wsum[1] + wsum[2] + wsum[3];
        int carry = carry_s;
        if (i < NN) off[i] = carry + pre + x - v;
        __syncthreads();
        if (threadIdx.x == 0) carry_s = carry + total;
        __syncthreads();
    }
    if (threadIdx.x == 0) off[NN] = carry_s;
}

// jr[e] = slot of edge e in rcv-CSR order
__global__ __launch_bounds__(256) void fill_kernel(const int* __restrict__ ei,
                                                   const int* __restrict__ off,
                                                   int* __restrict__ cur,
                                                   int* __restrict__ jr) {
    int e = blockIdx.x * 256 + threadIdx.x;
    if (e >= EE) return;
    int rcv = ei[EE + e];
    jr[e] = off[rcv] + atomicAdd(&cur[rcv], 1);
}

// -------------------- geometry: records in rcv-CSR order + E1 atomics ------------------

__global__ __launch_bounds__(256) void edge_geom(const float* __restrict__ pos,
                                                 const float* __restrict__ shifts,
                                                 const int* __restrict__ ei,
                                                 const float* __restrict__ wsh,
                                                 const int* __restrict__ jr,
                                                 float* __restrict__ rec,
                                                 float* __restrict__ E1) {
    int e = blockIdx.x * 256 + threadIdx.x;
    if (e >= EE) return;
    int snd = ei[e];
    int rcv = ei[EE + e];
    float vx = pos[rcv * 3 + 0] - pos[snd * 3 + 0] + shifts[e * 3 + 0];
    float vy = pos[rcv * 3 + 1] - pos[snd * 3 + 1] + shifts[e * 3 + 1];
    float vz = pos[rcv * 3 + 2] - pos[snd * 3 + 2] + shifts[e * 3 + 2];
    float r2 = vx * vx + vy * vy + vz * vz + 1e-12f;
    float r = sqrtf(r2);
    float inv_r = 1.0f / r;
    float x = vx * inv_r, y = vy * inv_r, z = vz * inv_r;
    float valid = (r < RMAXF) ? 1.f : 0.f;

    float s0 = shc_s(x, y, z, wsh);
    float s1v = shc_s(x, y, z, wsh + 16);

    float u = r * (1.0f / RMAXF);
    float th = PI_F * u;
    float s1 = sinf(th), c1 = cosf(th);
    float u2 = u * u, u3 = u2 * u, u5 = u2 * u3, u6 = u3 * u3, u7 = u6 * u, u8 = u6 * u2;
    float env = (1.f - 28.f * u6 + 48.f * u7 - 21.f * u8) * valid;
    float denv = (-168.f * u5 + 336.f * u6 - 168.f * u7) * (1.0f / RMAXF) * valid;
    float sk = s1, skm = 0.f, ck = c1, ckm = 1.f;
    float tc = 2.f * c1;
    float ebv[NBES], dbv[NBES];
#pragma unroll
    for (int k = 1; k <= NBES; k++) {
        float b = CCB * sk * inv_r;
        ebv[k - 1] = b * env;
        dbv[k - 1] = CCB * (((float)k * PI_F * (1.0f / RMAXF)) * ck * inv_r
                            - sk * inv_r * inv_r) * env
                     + b * denv;
        float sn = tc * sk - skm; skm = sk; sk = sn;
        float cn = tc * ck - ckm; ckm = ck; ck = cn;
    }

    // E1[n,k] = sum_{e: snd=n} eb[k] * s1
#pragma unroll
    for (int k = 0; k < NBES; k++)
        atomicAdd(&E1[(size_t)snd * 8 + k], ebv[k] * s1v);

    float* rc = rec + (size_t)jr[e] * RECW;
    *(float4*)&rc[0]  = make_float4(ebv[0], ebv[1], ebv[2], ebv[3]);
    *(float4*)&rc[4]  = make_float4(ebv[4], ebv[5], ebv[6], ebv[7]);
    *(float4*)&rc[8]  = make_float4(dbv[0], dbv[1], dbv[2], dbv[3]);
    *(float4*)&rc[12] = make_float4(dbv[4], dbv[5], dbv[6], dbv[7]);
    *(float4*)&rc[16] = make_float4(s0, s1v, x, y);
    *(float4*)&rc[20] = make_float4(z, inv_r, __int_as_float(snd), __int_as_float(rcv));
}

// -------------------- small precomputes --------------------

__global__ __launch_bounds__(128) void a1_kernel(const float* __restrict__ Wout1,
                                                 const float* __restrict__ wread1,
                                                 const float* __restrict__ Wskip1,
                                                 const float* __restrict__ ae,
                                                 float* __restrict__ a1,
                                                 float* __restrict__ askip) {
    int f = threadIdx.x;
    float s = 0.f;
    for (int k = 0; k < FF; k++) s += Wout1[f * FF + k] * wread1[k];
    a1[f] = s;
    if (f < 10) {
        float t = 0.f;
        for (int k = 0; k < FF; k++) t += Wskip1[f * FF + k] * wread1[k];
        askip[f] = t + ae[f];
    }
}

// c0[f'] = sum_f wread0[f] Wout0[f',f];  D[k,f'] = sum_f a1[f] Wr1[k,f] Wout0[f',f]
__global__ __launch_bounds__(128) void cd_kernel(const float* __restrict__ Wout0,
                                                 const float* __restrict__ wread0,
                                                 const float* __restrict__ a1,
                                                 const float* __restrict__ Wr1,
                                                 float* __restrict__ c0,
                                                 float* __restrict__ D) {
    int fp = threadIdx.x;
    float c = 0.f;
    float d[NBES];
#pragma unroll
    for (int k = 0; k < NBES; k++) d[k] = 0.f;
    for (int f = 0; f < FF; f++) {
        float w = Wout0[fp * FF + f];
        c += wread0[f] * w;
        float aw = a1[f] * w;
#pragma unroll
        for (int k = 0; k < NBES; k++) d[k] += aw * Wr1[k * FF + f];
    }
    c0[fp] = c;
#pragma unroll
    for (int k = 0; k < NBES; k++) D[k * FF + fp] = d[k];
}

// GW[p=a*8+k][f'] = sum_f W_emb[a,f] Wr0[k,f] Wout0[f,f']
__global__ __launch_bounds__(256) void gw_kernel(const float* __restrict__ W_emb,
                                                 const float* __restrict__ Wr0,
                                                 const float* __restrict__ Wout0,
                                                 float* __restrict__ GW) {
    int idx = blockIdx.x * 256 + threadIdx.x;
    if (idx >= 80 * FF) return;
    int fp = idx & 127;
    int p = idx >> 7;
    int a = p >> 3, k = p & 7;
    float s = 0.f;
    for (int f = 0; f < FF; f++)
        s += W_emb[a * FF + f] * Wr0[k * FF + f] * Wout0[f * FF + fp];
    GW[p * FF + fp] = s;
}

// T[k'][p0=k*10+a] = sum_f D[k',f] W_emb[a,f] Wr0[k,f];  Mc[p0] = sum_f c0[f] W_emb Wr0
__global__ __launch_bounds__(256) void tmc_kernel(const float* __restrict__ D,
                                                  const float* __restrict__ c0,
                                                  const float* __restrict__ W_emb,
                                                  const float* __restrict__ Wr0,
                                                  float* __restrict__ T,
                                                  float* __restrict__ Mc) {
    for (int i = threadIdx.x; i < 720; i += 256) {
        if (i < 640) {
            int kp = i / 80;
            int p0 = i - kp * 80;
            int k = p0 / 10, a = p0 - k * 10;
            float s = 0.f;
            for (int f = 0; f < FF; f++)
                s += D[kp * FF + f] * W_emb[a * FF + f] * Wr0[k * FF + f];
            T[i] = s;
        } else {
            int p0 = i - 640;
            int k = p0 / 10, a = p0 - k * 10;
            float s = 0.f;
            for (int f = 0; f < FF; f++)
                s += c0[f] * W_emb[a * FF + f] * Wr0[k * FF + f];
            Mc[p0] = s;
        }
    }
}

// -------------------- P0[n, p=a*8+k] = sum_{e:rcv=n} attrs[snd,a] eb[e,k] s0_e --------

#define P0_BLOCKS 2048
__global__ __launch_bounds__(256) void p0_kernel(const float* __restrict__ rec,
                                                 const int* __restrict__ off,
                                                 const float* __restrict__ attrs,
                                                 float* __restrict__ P0) {
    int wv = (blockIdx.x * 256 + threadIdx.x) >> 6;
    int lane = threadIdx.x & 63;
    int nwaves = P0_BLOCKS * 4;
    int a_lo = lane >> 3;
    int k_l = lane & 7;

    for (int n = wv; n < NN; n += nwaves) {
        int beg = off[n], end = off[n + 1];
        float acc = 0.f, acc2 = 0.f;
        for (int j = beg; j < end; j++) {
            const float* rc = rec + (size_t)j * RECW;
            float s0 = rc[16];
            int snd = __float_as_int(rc[22]);
            float eb = rc[k_l];
            float es = eb * s0;
            acc += attrs[snd * 10 + a_lo] * es;
            if (lane < 16) acc2 += attrs[snd * 10 + 8 + a_lo] * es;
        }
        P0[(size_t)n * 80 + lane] = acc;
        if (lane < 16) P0[(size_t)n * 80 + 64 + lane] = acc2;
    }
}

// -------------------- h1 GEMM: h1 = P0 @ GW + attrs @ Wskip0 ; node_e = h1.wread0 ------

#define GEMM_BLOCKS 512
__global__ __launch_bounds__(256, 2) void h1_gemm(const float* __restrict__ P0,
                                                  const float* __restrict__ GW,
                                                  const float* __restrict__ attrs,
                                                  const float* __restrict__ Wskip,
                                                  const float* __restrict__ wread,
                                                  float* __restrict__ h1,
                                                  float* __restrict__ node_e) {
    __shared__ float sb[80][FF];   // 40 KB
    __shared__ float sa[32][80];   // 10 KB
    int t = threadIdx.x;
#pragma unroll
    for (int j = 0; j < 10; j++) {
        int flat4 = j * 256 + t;     // 0..2559
        int row = flat4 >> 5;
        int col = (flat4 & 31) * 4;
        *(float4*)&sb[row][col] = *(const float4*)&GW[row * FF + col];
    }

    int g = t >> 5;
    int f0 = (t & 31) * 4;
    const int NTILES = (NN + 31) / 32;

    for (int tile = blockIdx.x; tile < NTILES; tile += GEMM_BLOCKS) {
        __syncthreads();
#pragma unroll
        for (int j = 0; j < 3; j++) {
            int flat4 = j * 256 + t;   // need 640
            if (flat4 < 640) {
                int row = flat4 / 20;
                int col = (flat4 - row * 20) * 4;
                int n = tile * 32 + row;
                float4 v = make_float4(0.f, 0.f, 0.f, 0.f);
                if (n < NN) v = *(const float4*)&P0[(size_t)n * 80 + col];
                *(float4*)&sa[row][col] = v;
            }
        }
        __syncthreads();

        float acc[4][4];
#pragma unroll
        for (int i = 0; i < 4; i++)
#pragma unroll
            for (int j = 0; j < 4; j++) acc[i][j] = 0.f;

        for (int kk = 0; kk < 80; kk += 4) {
            float4 bv0 = *(const float4*)&sb[kk + 0][f0];
            float4 bv1 = *(const float4*)&sb[kk + 1][f0];
            float4 bv2 = *(const float4*)&sb[kk + 2][f0];
            float4 bv3 = *(const float4*)&sb[kk + 3][f0];
#pragma unroll
            for (int ni = 0; ni < 4; ni++) {
                float4 av = *(const float4*)&sa[g * 4 + ni][kk];
                acc[ni][0] += av.x * bv0.x + av.y * bv1.x + av.z * bv2.x + av.w * bv3.x;
                acc[ni][1] += av.x * bv0.y + av.y * bv1.y + av.z * bv2.y + av.w * bv3.y;
                acc[ni][2] += av.x * bv0.z + av.y * bv1.z + av.z * bv2.z + av.w * bv3.z;
                acc[ni][3] += av.x * bv0.w + av.y * bv1.w + av.z * bv2.w + av.w * bv3.w;
            }
        }

#pragma unroll
        for (int ni = 0; ni < 4; ni++) {
            int n = tile * 32 + g * 4 + ni;
            bool valid = (n < NN);
#pragma unroll
            for (int a = 0; a < 10; a++) {
                float att = valid ? attrs[n * 10 + a] : 0.f;
                float4 wk = *(const float4*)&Wskip[a * FF + f0];
                acc[ni][0] += att * wk.x;
                acc[ni][1] += att * wk.y;
                acc[ni][2] += att * wk.z;
                acc[ni][3] += att * wk.w;
            }
            if (valid) {
                float4 out;
                out.x = acc[ni][0]; out.y = acc[ni][1];
                out.z = acc[ni][2]; out.w = acc[ni][3];
                *(float4*)&h1[(size_t)n * FF + f0] = out;
            }
            float4 wv = *(const float4*)&wread[f0];
            float p = acc[ni][0] * wv.x + acc[ni][1] * wv.y
                    + acc[ni][2] * wv.z + acc[ni][3] * wv.w;
#pragma unroll
            for (int o = 16; o > 0; o >>= 1) p += __shfl_xor(p, o);
            if (valid && (t & 31) == 0) node_e[n] = p;
        }
    }
}

// -------------------- t1[n,k] = sum_f a1[f] h1[n,f] Wr1[k,f] --------------------

__global__ __launch_bounds__(256) void t1_kernel(const float* __restrict__ h1,
                                                 const float* __restrict__ a1,
                                                 const float* __restrict__ Wr1,
                                                 float* __restrict__ t1) {
    int w = threadIdx.x >> 6;
    int lane = threadIdx.x & 63;
    int n = blockIdx.x * 4 + w;
    if (n >= NN) return;
    int f0 = lane, f1 = lane + 64;
    float v0 = a1[f0] * h1[(size_t)n * FF + f0];
    float v1 = a1[f1] * h1[(size_t)n * FF + f1];
    float p[NBES];
#pragma unroll
    for (int k = 0; k < NBES; k++)
        p[k] = v0 * Wr1[k * FF + f0] + v1 * Wr1[k * FF + f1];
#pragma unroll
    for (int o = 32; o > 0; o >>= 1) {
#pragma unroll
        for (int k = 0; k < NBES; k++) p[k] += __shfl_xor(p[k], o);
    }
    if (lane == 0) {
        *(float4*)&t1[(size_t)n * 8]     = make_float4(p[0], p[1], p[2], p[3]);
        *(float4*)&t1[(size_t)n * 8 + 4] = make_float4(p[4], p[5], p[6], p[7]);
    }
}

// -------------------- M[n][p0=k*10+a] = Mc + sum_k' E1[n,k'] T[k'][p0] ----------------

__global__ __launch_bounds__(256) void m_kernel(const float* __restrict__ E1,
                                                const float* __restrict__ T,
                                                const float* __restrict__ Mc,
                                                float* __restrict__ M) {
    __shared__ float sT[720];
    int t = threadIdx.x;
    for (int i = t; i < 720; i += 256) sT[i] = (i < 640) ? T[i] : Mc[i - 640];
    __syncthreads();
    int n = blockIdx.x * 256 + t;
    if (n >= NN) return;
    float4 ea = *(const float4*)&E1[(size_t)n * 8];
    float4 eb = *(const float4*)&E1[(size_t)n * 8 + 4];
    float e1v[8] = {ea.x, ea.y, ea.z, ea.w, eb.x, eb.y, eb.z, eb.w};
#pragma unroll
    for (int c = 0; c < 20; c++) {
        float4 m = *(const float4*)&sT[640 + c * 4];
#pragma unroll
        for (int kp = 0; kp < 8; kp++) {
            float4 tv = *(const float4*)&sT[kp * 80 + c * 4];
            m.x += e1v[kp] * tv.x;
            m.y += e1v[kp] * tv.y;
            m.z += e1v[kp] * tv.z;
            m.w += e1v[kp] * tv.w;
        }
        *(float4*)&M[(size_t)n * 80 + c * 4] = m;
    }
}

// -------------------- fused per-edge pass: dsp/drp both layers + energy1 + forces -----

#define EP_BLOCKS 512
__global__ __launch_bounds__(256) void edge_pass(const float* __restrict__ rec,
                                                 const float* __restrict__ t1,
                                                 const float* __restrict__ M,
                                                 const float* __restrict__ attrs,
                                                 const int* __restrict__ batch,
                                                 const float* __restrict__ wsh,
                                                 float* __restrict__ forces,
                                                 float* __restrict__ energy) {
    __shared__ float eacc[GG];
    int t = threadIdx.x;
    int lane = t & 63;
    if (t < GG) eacc[t] = 0.f;
    __syncthreads();

    for (int j0 = blockIdx.x * 256; j0 < EE; j0 += EP_BLOCKS * 256) {
        int j = j0 + t;
        bool act = (j < EE);
        int jc = act ? j : 0;
        const float* rc = rec + (size_t)jc * RECW;
        float4 q0 = *(const float4*)&rc[0];
        float4 q1 = *(const float4*)&rc[4];
        float4 q2 = *(const float4*)&rc[8];
        float4 q3 = *(const float4*)&rc[12];
        float4 q4 = *(const float4*)&rc[16];
        float4 q5 = *(const float4*)&rc[20];
        float eb[8] = {q0.x, q0.y, q0.z, q0.w, q1.x, q1.y, q1.z, q1.w};
        float db[8] = {q2.x, q2.y, q2.z, q2.w, q3.x, q3.y, q3.z, q3.w};
        float s0 = q4.x, s1v = q4.y, x = q4.z, y = q4.w;
        float z = q5.x, ivr = q5.y;
        int snd = __float_as_int(q5.z);
        int rcv = __float_as_int(q5.w);

        // layer 1: dsp1/drp1 via t1[snd]
        float4 ta = *(const float4*)&t1[(size_t)snd * 8];
        float4 tb = *(const float4*)&t1[(size_t)snd * 8 + 4];
        float tg[8] = {ta.x, ta.y, ta.z, ta.w, tb.x, tb.y, tb.z, tb.w};
        float dsp1 = 0.f, drp1 = 0.f;
#pragma unroll
        for (int k = 0; k < 8; k++) {
            dsp1 += eb[k] * tg[k];
            drp1 += db[k] * tg[k];
        }

        // layer 0: t0[k] = sum_a attrs[snd,a] M[rcv,k,a]
        float at[10];
#pragma unroll
        for (int i = 0; i < 5; i++) {
            float2 v = *(const float2*)&attrs[snd * 10 + 2 * i];
            at[2 * i] = v.x; at[2 * i + 1] = v.y;
        }
        const float* Mr = M + (size_t)rcv * 80;
        float dsp0 = 0.f, drp0 = 0.f;
#pragma unroll
        for (int k = 0; k < 8; k++) {
            float t0 = 0.f;
#pragma unroll
            for (int a = 0; a < 10; a++) t0 += at[a] * Mr[k * 10 + a];
            dsp0 += eb[k] * t0;
            drp0 += db[k] * t0;
        }

        // layer-1 energy contribution: s1 * dsp1, grouped by batch[rcv]
        float el = act ? s1v * dsp1 : 0.f;
        int b = act ? batch[rcv] : -1;
        int ub = __builtin_amdgcn_readfirstlane(b);
        if (__all(b == ub)) {
            float es = el;
#pragma unroll
            for (int o = 32; o > 0; o >>= 1) es += __shfl_xor(es, o);
            if (lane == 0 && ub >= 0) atomicAdd(&eacc[ub], es);
        } else {
            if (act) atomicAdd(&eacc[b], el);
        }

        // forces
        float g0x, g0y, g0z, g1x, g1y, g1z;
        shc_grad(x, y, z, wsh, g0x, g0y, g0z);
        shc_grad(x, y, z, wsh + 16, g1x, g1y, g1z);
        float gux = dsp0 * g0x + dsp1 * g1x;
        float guy = dsp0 * g0y + dsp1 * g1y;
        float guz = dsp0 * g0z + dsp1 * g1z;
        float gr = s0 * drp0 + s1v * drp1;
        float dgu = gux * x + guy * y + guz * z;
        float gvx = gr * x + ivr * (gux - dgu * x);
        float gvy = gr * y + ivr * (guy - dgu * y);
        float gvz = gr * z + ivr * (guz - dgu * z);
        if (act) {
            atomicAdd(&forces[snd * 3 + 0], gvx);
            atomicAdd(&forces[snd * 3 + 1], gvy);
            atomicAdd(&forces[snd * 3 + 2], gvz);
            atomicAdd(&forces[rcv * 3 + 0], -gvx);
            atomicAdd(&forces[rcv * 3 + 1], -gvy);
            atomicAdd(&forces[rcv * 3 + 2], -gvz);
        }
    }
    __syncthreads();
    if (t < GG && eacc[t] != 0.f) atomicAdd(&energy[t], eacc[t]);
}

// -------------------- energy finalize: node_e + attrs.askip --------------------

#define EF_BLOCKS 128
__global__ __launch_bounds__(256) void efinal_kernel(const float* __restrict__ node_e,
                                                     const float* __restrict__ attrs,
                                                     const float* __restrict__ askip,
                                                     const int* __restrict__ batch,
                                                     float* __restrict__ energy) {
    __shared__ float eacc[GG];
    int t = threadIdx.x;
    if (t < GG) eacc[t] = 0.f;
    __syncthreads();
    for (int n = blockIdx.x * 256 + t; n < NN; n += EF_BLOCKS * 256) {
        float v = node_e[n];
#pragma unroll
        for (int a = 0; a < 10; a++) v += attrs[n * 10 + a] * askip[a];
        atomicAdd(&eacc[batch[n]], v);
    }
    __syncthreads();
    if (t < GG && eacc[t] != 0.f) atomicAdd(&energy[t], eacc[t]);
}

// -------------------- launch --------------------

extern "C" void kernel_launch(void* const* d_in, const int* in_sizes, int n_in,
                              void* d_out, int out_size, void* d_ws, size_t ws_size,
                              hipStream_t stream) {
    const float* pos    = (const float*)d_in[0];
    const float* attrs  = (const float*)d_in[1];
    const float* shifts = (const float*)d_in[2];
    const int*   ei     = (const int*)d_in[3];
    const int*   batch  = (const int*)d_in[4];
    const float* W_emb  = (const float*)d_in[6];
    const float* ae     = (const float*)d_in[7];
    const float* W_r    = (const float*)d_in[8];   // (2,8,F)
    const float* w_sh   = (const float*)d_in[9];   // (2,16)
    const float* W_out  = (const float*)d_in[10];  // (2,F,F)
    const float* W_skip = (const float*)d_in[11];  // (2,10,F)
    const float* w_read = (const float*)d_in[12];  // (2,F)

    const float* Wr0 = W_r;
    const float* Wr1 = W_r + NBES * FF;
    const float* Wout0 = W_out;
    const float* Wout1 = W_out + FF * FF;

    float* energy = (float*)d_out;
    float* forces = energy + GG;

    float* ws  = (float*)d_ws;
    float* h1  = ws;                        // N*F
    float* P0  = h1 + (size_t)NN * FF;      // N*80
    float* M   = P0 + (size_t)NN * 80;      // N*80
    float* E1  = M + (size_t)NN * 80;       // N*8
    float* t1  = E1 + (size_t)NN * 8;       // N*8
    float* node_e = t1 + (size_t)NN * 8;    // N
    float* rec = node_e + NN;               // EE*24
    float* a1  = rec + (size_t)EE * RECW;   // 128
    float* askip = a1 + FF;                 // 16
    float* c0  = askip + 16;                // 128
    float* D   = c0 + FF;                   // 8*128
    float* GW  = D + NBES * FF;             // 80*128
    float* T   = GW + 80 * FF;              // 640
    float* Mc  = T + 640;                   // 80

    int* cnt = (int*)(Mc + 80);             // N
    int* cur = cnt + NN;                    // N
    int* off = cur + NN;                    // N+1
    int* jr  = off + NN + 1;                // EE

    const int edgeBlocks = (EE + 255) / 256;

    hipMemsetAsync(d_out, 0, (size_t)out_size * sizeof(float), stream);
    hipMemsetAsync(E1, 0, (size_t)NN * 8 * sizeof(float), stream);
    hipMemsetAsync(cnt, 0, (size_t)2 * NN * sizeof(int), stream);   // cnt + cur

    // CSR (rcv) + record placement
    count_kernel<<<edgeBlocks, 256, 0, stream>>>(ei, cnt);
    scan_kernel<<<1, 256, 0, stream>>>(cnt, off);
    fill_kernel<<<edgeBlocks, 256, 0, stream>>>(ei, off, cur, jr);

    // small precomputes
    a1_kernel<<<1, 128, 0, stream>>>(Wout1, w_read + FF, W_skip + 10 * FF, ae, a1, askip);
    cd_kernel<<<1, 128, 0, stream>>>(Wout0, w_read, a1, Wr1, c0, D);
    gw_kernel<<<40, 256, 0, stream>>>(W_emb, Wr0, Wout0, GW);
    tmc_kernel<<<1, 256, 0, stream>>>(D, c0, W_emb, Wr0, T, Mc);

    // geometry + E1
    edge_geom<<<edgeBlocks, 256, 0, stream>>>(pos, shifts, ei, w_sh, jr, rec, E1);

    // P0, then h1, t1, M
    p0_kernel<<<P0_BLOCKS, 256, 0, stream>>>(rec, off, attrs, P0);
    h1_gemm<<<GEMM_BLOCKS, 256, 0, stream>>>(P0, GW, attrs, W_skip, w_read, h1, node_e);
    t1_kernel<<<(NN + 3) / 4, 256, 0, stream>>>(h1, a1, Wr1, t1);
    m_kernel<<<(NN + 255) / 256, 256, 0, stream>>>(E1, T, Mc, M);

    // fused per-edge: dsp/drp both layers, layer-1 energy, forces
    edge_pass<<<EP_BLOCKS, 256, 0, stream>>>(rec, t1, M, attrs, batch, w_sh,
                                             forces, energy);

    // energy finalize (layer-0 node energies + layer-1 skip + e0)
    efinal_kernel<<<EF_BLOCKS, 256, 0, stream>>>(node_e, attrs, askip, batch, energy);
}